// Round 7
// baseline (170.681 us; speedup 1.0000x reference)
//
#include <hip/hip_runtime.h>
#include <hip/hip_bf16.h>
#include <math.h>

// Problem constants
#define C_DIM 256      // channels
#define SPAT 4096      // h*w = 64*64
#define HEADS_N 8
#define DHEAD 64
#define MEMTOK 4
#define TTOK 4100      // MEMTOK + SPAT
#define TTOKP 4224     // padded (66 tiles of 64; attn uses tiles 0..64)
#define HID 512        // HEADS_N * DHEAD
#define PSP 72         // epilogue LDS row pitch in bf16 elems (16B-aligned)

typedef __bf16 bf16x8 __attribute__((ext_vector_type(8)));
typedef unsigned short u16x8 __attribute__((ext_vector_type(8)));
typedef float f32x4 __attribute__((ext_vector_type(4)));

static __device__ inline unsigned short f2bf(float f) {  // RNE f32->bf16
    unsigned int u = __float_as_uint(f);
    u += 0x7fffu + ((u >> 16) & 1u);
    return (unsigned short)(u >> 16);
}

static __device__ inline bf16x8 ldb8(const void* p) {
    union { u16x8 u; bf16x8 b; } t;
    t.u = *(const u16x8*)p;
    return t.b;
}

static __device__ inline unsigned int pkbf(float a, float b) {  // packed bf16 pair
    union { __bf16 h[2]; unsigned int u; } t;
    t.h[0] = (__bf16)a; t.h[1] = (__bf16)b;
    return t.u;
}

// inverse of the per-32-token V key-permutation pi (pi: [b4b3b2]->[b2b4b3]).
static __device__ inline int pinv(int m) {
    return (m & 3) | (((m >> 4) & 1) << 2) | (((m >> 2) & 3) << 3);
}

// async global->LDS, 16B per lane (LDS dest = wave-uniform base + lane*16)
static __device__ inline void gload16(const void* g, void* l) {
    __builtin_amdgcn_global_load_lds(
        (const __attribute__((address_space(1))) unsigned int*)g,
        (__attribute__((address_space(3))) unsigned int*)l, 16, 0, 0);
}

#define DRAIN_BAR() do { \
    asm volatile("s_waitcnt vmcnt(0)\n\ts_barrier" ::: "memory"); \
    __builtin_amdgcn_sched_barrier(0); } while (0)

// ---------------------------------------------------------------------------
// Kernel 1: prep — all elementwise work, one launch, 1088 blocks.  (unchanged)
// ---------------------------------------------------------------------------
__global__ __launch_bounds__(256) void prep_kernel(
    const float* __restrict__ x, const float* __restrict__ gamma,
    const float* __restrict__ mem, const float* __restrict__ wq,
    const float* __restrict__ wo,
    unsigned short* __restrict__ xb, float* __restrict__ spb,
    unsigned short* __restrict__ wb, unsigned short* __restrict__ wob,
    unsigned short* __restrict__ kb, unsigned short* __restrict__ vtb) {
    __shared__ float XT[64][65];
    __shared__ float red[4][64];
    const int bid = blockIdx.x;
    const int t = threadIdx.x;
    if (bid < 256) {              // A: transpose-cast x
        int p0 = (bid & 63) * 64, c0 = (bid >> 6) * 64;
#pragma unroll
        for (int i = 0; i < 4; ++i) {
            int cl = i * 16 + (t >> 4), p4 = (t & 15) * 4;
            *(float4*)&XT[cl][p4] = *(const float4*)&x[(size_t)(c0 + cl) * SPAT + p0 + p4];
        }
        __syncthreads();
        int pl = t >> 2, cs = (t & 3) * 16;
        u16x8 a, b;
#pragma unroll
        for (int j = 0; j < 8; ++j) a[j] = f2bf(XT[cs + j][pl]);
#pragma unroll
        for (int j = 0; j < 8; ++j) b[j] = f2bf(XT[cs + 8 + j][pl]);
        *(u16x8*)&xb[(size_t)(p0 + pl) * C_DIM + c0 + cs] = a;
        *(u16x8*)&xb[(size_t)(p0 + pl) * C_DIM + c0 + cs + 8] = b;
    } else if (bid < 320) {       // B: norms
        int p = (bid - 256) * 64 + (t & 63);
        int g = t >> 6;
        float ss = 0.f;
        for (int c = g * 64; c < g * 64 + 64; ++c) {
            float v = x[(size_t)c * SPAT + p];
            ss += v * v;
        }
        red[g][t & 63] = ss;
        __syncthreads();
        if (g == 0) {
            int lp = t & 63;
            float tot = red[0][lp] + red[1][lp] + red[2][lp] + red[3][lp];
            spb[p] = rsqrtf(tot) * 16.0f;
        }
    } else if (bid < 512) {       // C: wb = bf16(wq * (gamma+1)), 8 elems/thread
        size_t idx = ((size_t)(bid - 320) * 256 + t) * 8;
        int c0 = (int)(idx & 255);
        float4 f0 = *(const float4*)&wq[idx];
        float4 f1 = *(const float4*)&wq[idx + 4];
        float4 g0 = *(const float4*)&gamma[c0];
        float4 g1 = *(const float4*)&gamma[c0 + 4];
        u16x8 pk;
        pk[0] = f2bf(f0.x * (g0.x + 1.f)); pk[1] = f2bf(f0.y * (g0.y + 1.f));
        pk[2] = f2bf(f0.z * (g0.z + 1.f)); pk[3] = f2bf(f0.w * (g0.w + 1.f));
        pk[4] = f2bf(f1.x * (g1.x + 1.f)); pk[5] = f2bf(f1.y * (g1.y + 1.f));
        pk[6] = f2bf(f1.z * (g1.z + 1.f)); pk[7] = f2bf(f1.w * (g1.w + 1.f));
        *(u16x8*)&wb[idx] = pk;
    } else if (bid < 576) {       // D: wob = bf16(wo)
        size_t idx = ((size_t)(bid - 512) * 256 + t) * 8;
        float4 f0 = *(const float4*)&wo[idx];
        float4 f1 = *(const float4*)&wo[idx + 4];
        u16x8 pk;
        pk[0] = f2bf(f0.x); pk[1] = f2bf(f0.y); pk[2] = f2bf(f0.z); pk[3] = f2bf(f0.w);
        pk[4] = f2bf(f1.x); pk[5] = f2bf(f1.y); pk[6] = f2bf(f1.z); pk[7] = f2bf(f1.w);
        *(u16x8*)&wob[idx] = pk;
    } else {                      // E: mem_kv + zero pads (131072 threads)
        int i = (bid - 576) * 256 + t;
        if (i < 4096) {
            int d = i & 63, m = (i >> 6) & 3, h = (i >> 8) & 7, s = (i >> 11) & 1;
            unsigned short val = f2bf(mem[i]);
            if (s == 0) kb[(size_t)h * TTOKP * 64 + m * 64 + d] = val;
            else        vtb[((size_t)h * 64 + d) * TTOKP + m] = val;
        } else {
            int z = i - 4096;              // 0..126975
            if (z < 63488) {               // kb pad rows 4100..4223 (124/head)
                int h = z / 7936, r = z % 7936;
                int row = TTOK + r / 64, d = r % 64;
                kb[(size_t)h * TTOKP * 64 + row * 64 + d] = 0;
            } else {                       // vtb pad cols 4100..4223
                z -= 63488;
                int h = z / 7936, r = z % 7936;
                int d = r / 124, tcol = TTOK + r % 124;
                vtb[((size_t)h * 64 + d) * TTOKP + tcol] = 0;
            }
        }
    }
}

// ---------------------------------------------------------------------------
// Kernel 2: QKV GEMM on MFMA (bf16 in, fp32 accum, bf16 out).  (unchanged)
// ---------------------------------------------------------------------------
__global__ __launch_bounds__(256) void qkv_mfma(const unsigned short* __restrict__ wb,
                                                const unsigned short* __restrict__ xb,
                                                const float* __restrict__ spb,
                                                unsigned short* __restrict__ qb,
                                                unsigned short* __restrict__ kb,
                                                unsigned short* __restrict__ vtb) {
    const int tile_p = blockIdx.x;      // 0..63
    const int tile_o = blockIdx.y;      // 0..23
    const int p0 = tile_p * 64, o0 = tile_o * 64;
    __shared__ unsigned short LB[4][64 * 128];  // W0,X0,W1,X1 chunk buffers

    const int t = threadIdx.x;
    const int w = t >> 6, lane = t & 63;
    const int col16 = lane & 15, quad = lane >> 4;
    const int c7 = col16 & 7;
    const char* gw = (const char*)(wb + (size_t)o0 * C_DIM);
    const char* gx = (const char*)(xb + (size_t)p0 * C_DIM);

    auto STG = [&](int ck, unsigned short* SWb, unsigned short* SXb) {
#pragma unroll
        for (int i = 0; i < 4; ++i) {
            int c4 = w * 4 + i;                       // 1KB chunk
            int row = c4 * 4 + (lane >> 4);           // 0..63
            int sl = (((lane & 15) ^ (row & 7)) << 4);
            size_t src = (size_t)row * 512 + ck * 256 + sl;
            gload16(gw + src, (char*)SWb + c4 * 1024);
            gload16(gx + src, (char*)SXb + c4 * 1024);
        }
    };

    f32x4 acc[4];
#pragma unroll
    for (int n = 0; n < 4; ++n) acc[n] = (f32x4){0.f, 0.f, 0.f, 0.f};
    const int arow = (w * 16 + col16) * 256;

    auto COMP = [&](const unsigned short* SWb, const unsigned short* SXb) {
#pragma unroll
        for (int kkl = 0; kkl < 4; ++kkl) {
            int ko = (((kkl * 4 + quad) ^ c7) << 4);
            bf16x8 a = ldb8((const char*)SWb + arow + ko);
#pragma unroll
            for (int n = 0; n < 4; ++n) {
                bf16x8 b = ldb8((const char*)SXb + (n * 16 + col16) * 256 + ko);
                acc[n] = __builtin_amdgcn_mfma_f32_16x16x32_bf16(a, b, acc[n], 0, 0, 0);
            }
        }
    };

    STG(0, LB[0], LB[1]);
    DRAIN_BAR();
    STG(1, LB[2], LB[3]);     // prefetch chunk 1 under chunk-0 compute
    COMP(LB[0], LB[1]);
    DRAIN_BAR();
    COMP(LB[2], LB[3]);

    // --- epilogue: apply sp[p] (and QSC for q), store ---
    float spv[4];
#pragma unroll
    for (int n = 0; n < 4; ++n) spv[n] = spb[p0 + n * 16 + col16];

    const int sec = tile_o >> 3, h = tile_o & 7;
    if (sec < 2) {
        const float qsc = (sec == 0) ? 0.125f * 1.4426950408889634f : 1.0f;
        unsigned short* Ot = &LB[0][0];               // reuse, pitch PSP
        __syncthreads();                              // all MFMA LDS reads done
#pragma unroll
        for (int n = 0; n < 4; ++n) {
            float s = qsc * spv[n];
            ushort4 v4 = {f2bf(acc[n][0] * s), f2bf(acc[n][1] * s),
                          f2bf(acc[n][2] * s), f2bf(acc[n][3] * s)};
            *(ushort4*)&Ot[(n * 16 + col16) * PSP + w * 16 + quad * 4] = v4;
        }
        __syncthreads();
        int prow = t >> 2, dseg = t & 3;
        u16x8 va = *(u16x8*)&Ot[prow * PSP + dseg * 16];
        u16x8 vb = *(u16x8*)&Ot[prow * PSP + dseg * 16 + 8];
        unsigned short* dst = (sec == 0)
            ? qb + (size_t)h * SPAT * 64 + (size_t)(p0 + prow) * 64
            : kb + (size_t)h * TTOKP * 64 + (size_t)(MEMTOK + p0 + prow) * 64;
        *(u16x8*)&dst[dseg * 16] = va;
        *(u16x8*)&dst[dseg * 16 + 8] = vb;
    } else {   // v: scatter to vtb[h][d][pinv-permuted token col]
        unsigned short* dst = vtb + (size_t)h * 64 * TTOKP;
#pragma unroll
        for (int n = 0; n < 4; ++n) {
            int tg = MEMTOK + p0 + n * 16 + col16;
            int c = (tg & ~31) | pinv(tg & 31);
            float s = spv[n];
#pragma unroll
            for (int r = 0; r < 4; ++r)
                dst[(size_t)(w * 16 + quad * 4 + r) * TTOKP + c] = f2bf(acc[n][r] * s);
        }
    }
}

// ---------------------------------------------------------------------------
// Kernel 3: flash attention, Q-SPLIT + intra-block key-split.
// Block = (head, 32 q-rows); grid 1024 -> 4 blocks/CU (32KB LDS).
// Waves: w = (g<<1)|qsub is WRONG — mapping: qsub = w&1 (q-subtile 0/1),
// g = w>>1 (key half).  Waves g=0 handle keys [0,32) of every 64-key tile,
// g=1 handle keys [32,64); both share one staged K/V stream (double-buffered
// global_load_lds, fused vmcnt(0)+s_barrier per tile — R2/R5-verified).
// Per-wave online softmax on its key half (register-P PV, pi-permuted V);
// final fp32 merge across the two halves via LDS (__syncthreads-synced).
// Output obb[p][h*64+d] bf16 (same as R5).
// ---------------------------------------------------------------------------
__global__ __launch_bounds__(256, 4) void attn_mfma(const unsigned short* __restrict__ qb,
                                                    const unsigned short* __restrict__ kb,
                                                    const unsigned short* __restrict__ vtb,
                                                    unsigned short* __restrict__ obb) {
    const int h  = blockIdx.x & 7;           // head-pinned XCD locality
    const int p0 = (blockIdx.x >> 3) * 32;   // 32-row q tile

    __shared__ unsigned short LA[4][64 * 64];   // Ks0,Vs0,Ks1,Vs1 (8KB each)

    const int t = threadIdx.x;
    const int w = t >> 6;
    const int lane = t & 63;
    const int col16 = lane & 15;
    const int quad = lane >> 4;
    const int qsub = w & 1;       // q sub-tile (rows qsub*16..+15)
    const int g = w >> 1;         // key half (keys g*32..g*32+31 of each tile)
    const int cswz = col16 & 7;
    const int sw0 = ((quad ^ cswz) << 4);
    const int sw1 = (((quad + 4) ^ cswz) << 4);

    const unsigned short* qh = qb + (size_t)h * SPAT * 64;
    const char* khb = (const char*)(kb + (size_t)h * TTOKP * 64);
    const char* vhb = (const char*)(vtb + (size_t)h * 64 * TTOKP);

    bf16x8 aq0 = ldb8(&qh[(size_t)(p0 + qsub * 16 + col16) * 64 + quad * 8]);
    bf16x8 aq1 = ldb8(&qh[(size_t)(p0 + qsub * 16 + col16) * 64 + 32 + quad * 8]);

    float m_i = -1e30f, l_i = 0.f;
    f32x4 Oa[4];
#pragma unroll
    for (int n = 0; n < 4; ++n) Oa[n] = (f32x4){0.f, 0.f, 0.f, 0.f};

    // stage one 64-key tile (all 4 waves): K = 64 rows x 128B, V = 64 d x 128B
    auto STAGE = [&](int tb, unsigned short* Kd, unsigned short* Vd) {
#pragma unroll
        for (int i = 0; i < 2; ++i) {
            int ck = w * 2 + i;                              // 1KB chunks 0..7
            int row = ck * 8 + (lane >> 3);                  // 0..63
            int col = (((lane & 7) ^ (lane >> 3)) << 4);     // row&7 == lane>>3
            gload16(khb + (size_t)(tb * 64 + row) * 128 + col, (char*)Kd + ck * 1024);
            gload16(vhb + (size_t)row * (TTOKP * 2) + (size_t)tb * 128 + col,
                    (char*)Vd + ck * 1024);
        }
    };

    auto STEP = [&](int tile, const unsigned short* Kc_, const unsigned short* Vc_,
                    unsigned short* Ksn, unsigned short* Vsn, bool stage, bool mask) {
        if (stage) STAGE(tile + 1, Ksn, Vsn);

        const char* Kc = (const char*)Kc_;
        const char* Vc = (const char*)Vc_;

        // S^T on this wave's key half: sv[nn][r] = key g*32 + nn*16 + quad*4 + r
        f32x4 sv[2];
#pragma unroll
        for (int nn = 0; nn < 2; ++nn) {
            int n = g * 2 + nn;
            sv[nn] = (f32x4){0.f, 0.f, 0.f, 0.f};
            bf16x8 bk0 = ldb8(Kc + (n * 16 + col16) * 128 + sw0);
            bf16x8 bk1 = ldb8(Kc + (n * 16 + col16) * 128 + sw1);
            sv[nn] = __builtin_amdgcn_mfma_f32_16x16x32_bf16(bk0, aq0, sv[nn], 0, 0, 0);
            sv[nn] = __builtin_amdgcn_mfma_f32_16x16x32_bf16(bk1, aq1, sv[nn], 0, 0, 0);
        }

        if (mask) {   // tile 64: only tokens 4096..4099 (g==0, nn==0, quad==0)
#pragma unroll
            for (int nn = 0; nn < 2; ++nn)
#pragma unroll
                for (int r = 0; r < 4; ++r)
                    if ((g | nn | quad) != 0) sv[nn][r] = -1e30f;
        }

        // row max over this wave's 32 keys: 7 local fmax + 2 shfl
        float rm = fmaxf(fmaxf(fmaxf(sv[0][0], sv[0][1]), fmaxf(sv[0][2], sv[0][3])),
                         fmaxf(fmaxf(sv[1][0], sv[1][1]), fmaxf(sv[1][2], sv[1][3])));
        rm = fmaxf(rm, __shfl_xor(rm, 16, 64));
        rm = fmaxf(rm, __shfl_xor(rm, 32, 64));

        float mn = fmaxf(m_i, rm);
        float al = __builtin_amdgcn_exp2f(m_i - mn);
        m_i = mn;

        float sm[2];
#pragma unroll
        for (int nn = 0; nn < 2; ++nn) {
            float e0 = __builtin_amdgcn_exp2f(sv[nn][0] - mn);
            float e1 = __builtin_amdgcn_exp2f(sv[nn][1] - mn);
            float e2 = __builtin_amdgcn_exp2f(sv[nn][2] - mn);
            float e3 = __builtin_amdgcn_exp2f(sv[nn][3] - mn);
            sv[nn][0] = e0; sv[nn][1] = e1; sv[nn][2] = e2; sv[nn][3] = e3;
            sm[nn] = (e0 + e1) + (e2 + e3);
        }
        float rs = sm[0] + sm[1];
        rs += __shfl_xor(rs, 16, 64);
        rs += __shfl_xor(rs, 32, 64);
        l_i = l_i * al + rs;

#pragma unroll
        for (int n = 0; n < 4; ++n) {
            Oa[n][0] *= al; Oa[n][1] *= al; Oa[n][2] *= al; Oa[n][3] *= al;
        }

        // PV over this wave's 32 keys (pi-permuted V): one f-group = g
        union { unsigned int u[4]; bf16x8 v; } pu;
        pu.u[0] = pkbf(sv[0][0], sv[0][1]);
        pu.u[1] = pkbf(sv[0][2], sv[0][3]);
        pu.u[2] = pkbf(sv[1][0], sv[1][1]);
        pu.u[3] = pkbf(sv[1][2], sv[1][3]);
        int vo = (((g * 4 + quad) ^ cswz) << 4);
#pragma unroll
        for (int n = 0; n < 4; ++n) {
            bf16x8 bv = ldb8(Vc + (n * 16 + col16) * 128 + vo);
            Oa[n] = __builtin_amdgcn_mfma_f32_16x16x32_bf16(bv, pu.v, Oa[n], 0, 0, 0);
        }

        if (!mask) DRAIN_BAR();
    };

    STAGE(0, LA[0], LA[1]);
    DRAIN_BAR();
    for (int b = 0; b < 64; b += 2) {
        STEP(b,     LA[0], LA[1], LA[2], LA[3], true, false);
        STEP(b + 1, LA[2], LA[3], LA[0], LA[1], true, false);
    }
    STEP(64, LA[0], LA[1], LA[2], LA[3], false, true);   // no stage, masked

    // ---- intra-block merge of the two key halves (fp32) + store obb ----
    __syncthreads();                                  // all staging reads done
    float* MB = (float*)&LA[0][0];                    // [32 q][68] f32 = 8704B
    float2* ML = (float2*)((char*)&LA[0][0] + 8704);  // 32 float2
    __bf16* TR = (__bf16*)&LA[2][0];                  // transpose region (g=0)

    if (g == 1) {                 // publish partial (m,l,O) for q-row col16
        float* row = MB + (qsub * 16 + col16) * 68;
#pragma unroll
        for (int n = 0; n < 4; ++n)
#pragma unroll
            for (int r = 0; r < 4; ++r)
                row[n * 16 + quad * 4 + r] = Oa[n][r];
        if (quad == 0) ML[qsub * 16 + col16] = make_float2(m_i, l_i);
    }
    __syncthreads();
    if (g == 0) {
        float2 o = ML[qsub * 16 + col16];
        float M = fmaxf(m_i, o.x);
        float a0 = __builtin_amdgcn_exp2f(m_i - M);
        float a1 = __builtin_amdgcn_exp2f(o.x - M);
        float inv = 1.0f / (a0 * l_i + a1 * o.y);
        const float* row = MB + (qsub * 16 + col16) * 68;
        __bf16* ot = TR + (size_t)qsub * 16 * PSP;    // per-wave region
#pragma unroll
        for (int n = 0; n < 4; ++n) {
            float v0 = (a0 * Oa[n][0] + a1 * row[n * 16 + quad * 4 + 0]) * inv;
            float v1 = (a0 * Oa[n][1] + a1 * row[n * 16 + quad * 4 + 1]) * inv;
            float v2 = (a0 * Oa[n][2] + a1 * row[n * 16 + quad * 4 + 2]) * inv;
            float v3 = (a0 * Oa[n][3] + a1 * row[n * 16 + quad * 4 + 3]) * inv;
            *(unsigned int*)&ot[col16 * PSP + n * 16 + quad * 4]     = pkbf(v0, v1);
            *(unsigned int*)&ot[col16 * PSP + n * 16 + quad * 4 + 2] = pkbf(v2, v3);
        }
        int q2 = lane >> 2, dseg = (lane & 3) * 16;
        const unsigned short* otr = (const unsigned short*)ot;
        u16x8 o0v = *(const u16x8*)&otr[q2 * PSP + dseg];
        u16x8 o1v = *(const u16x8*)&otr[q2 * PSP + dseg + 8];
        unsigned short* dst = obb + (size_t)(p0 + qsub * 16 + q2) * HID + h * DHEAD + dseg;
        *(u16x8*)&dst[0] = o0v;
        *(u16x8*)&dst[8] = o1v;
    }
}

// ---------------------------------------------------------------------------
// Kernel 4: out projection on MFMA (bf16 in, fp32 accum, fp32 out).
// out[o][p] = sum_hd wob[o][hd] * obb[p][hd].  K=512 as 4 chunks of 128,
// double-buffered staging.  (R5 version, verbatim — verified at 156.9us.)
// ---------------------------------------------------------------------------
__global__ __launch_bounds__(256) void out_mfma(const unsigned short* __restrict__ wob,
                                                const unsigned short* __restrict__ obb,
                                                float* __restrict__ out) {
    const int p0 = blockIdx.x * 64;
    const int o0 = blockIdx.y * 64;
    __shared__ unsigned short LB[4][64 * 128];   // W0,O0,W1,O1 chunk buffers

    const int t = threadIdx.x;
    const int w = t >> 6, lane = t & 63;
    const int col16 = lane & 15, quad = lane >> 4;
    const int c7 = col16 & 7;
    const char* gw = (const char*)(wob + (size_t)o0 * HID);
    const char* go = (const char*)(obb + (size_t)p0 * HID);

    auto STG = [&](int ck, unsigned short* SWb, unsigned short* SOb) {
#pragma unroll
        for (int i = 0; i < 4; ++i) {
            int c4 = w * 4 + i;
            int row = c4 * 4 + (lane >> 4);
            int sl = (((lane & 15) ^ (row & 7)) << 4);
            size_t src = (size_t)row * 1024 + ck * 256 + sl;
            gload16(gw + src, (char*)SWb + c4 * 1024);
            gload16(go + src, (char*)SOb + c4 * 1024);
        }
    };

    f32x4 acc[4];
#pragma unroll
    for (int n = 0; n < 4; ++n) acc[n] = (f32x4){0.f, 0.f, 0.f, 0.f};
    const int arow = (w * 16 + col16) * 256;

    auto COMP = [&](const unsigned short* SWb, const unsigned short* SOb) {
#pragma unroll
        for (int kkl = 0; kkl < 4; ++kkl) {
            int ko = (((kkl * 4 + quad) ^ c7) << 4);
            bf16x8 a = ldb8((const char*)SWb + arow + ko);
#pragma unroll
            for (int n = 0; n < 4; ++n) {
                bf16x8 b = ldb8((const char*)SOb + (n * 16 + col16) * 256 + ko);
                acc[n] = __builtin_amdgcn_mfma_f32_16x16x32_bf16(a, b, acc[n], 0, 0, 0);
            }
        }
    };

    STG(0, LB[0], LB[1]);
    DRAIN_BAR();
    STG(1, LB[2], LB[3]);  COMP(LB[0], LB[1]);  DRAIN_BAR();
    STG(2, LB[0], LB[1]);  COMP(LB[2], LB[3]);  DRAIN_BAR();
    STG(3, LB[2], LB[3]);  COMP(LB[0], LB[1]);  DRAIN_BAR();
    COMP(LB[2], LB[3]);

    // epilogue: D[o][p] -> per-wave LDS transpose -> coalesced float4 stores
    __syncthreads();
    float* otw = (float*)&LB[0][0] + (size_t)w * (16 * 68);
#pragma unroll
    for (int n = 0; n < 4; ++n)
#pragma unroll
        for (int r = 0; r < 4; ++r)
            otw[(quad * 4 + r) * 68 + n * 16 + col16] = acc[n][r];
    int r2 = lane >> 2, csg = (lane & 3) * 16;
#pragma unroll
    for (int j = 0; j < 4; ++j) {
        float4 v = *(const float4*)&otw[r2 * 68 + csg + j * 4];
        *(float4*)&out[(size_t)(o0 + w * 16 + r2) * SPAT + p0 + csg + j * 4] = v;
    }
}

// ---------------------------------------------------------------------------
// Launch
// ---------------------------------------------------------------------------
extern "C" void kernel_launch(void* const* d_in, const int* in_sizes, int n_in,
                              void* d_out, int out_size, void* d_ws, size_t ws_size,
                              hipStream_t stream) {
    const float* x      = (const float*)d_in[0];
    const float* gamma  = (const float*)d_in[1];
    const float* mem_kv = (const float*)d_in[2];
    const float* w_qkv  = (const float*)d_in[3];
    const float* w_out  = (const float*)d_in[4];
    float* out = (float*)d_out;

    // workspace (bf16 unless noted): xb | wb | wob | qb | kb | vtb | obb | spb(f32)
    unsigned short* xb  = (unsigned short*)d_ws;                 // 4096*256
    unsigned short* wb  = xb + (size_t)SPAT * C_DIM;             // 1536*256
    unsigned short* wob = wb + (size_t)3 * HID * C_DIM;          // 256*512
    unsigned short* qb  = wob + (size_t)C_DIM * HID;             // 8*4096*64
    unsigned short* kb  = qb + (size_t)HEADS_N * SPAT * DHEAD;   // 8*4224*64
    unsigned short* vtb = kb + (size_t)HEADS_N * TTOKP * DHEAD;  // 8*64*4224
    unsigned short* obb = vtb + (size_t)HEADS_N * DHEAD * TTOKP; // 4096*512
    float* spb = (float*)(obb + (size_t)SPAT * HID);             // 4096

    prep_kernel<<<dim3(1088), 256, 0, stream>>>(x, gamma, mem_kv, w_qkv, w_out,
                                                xb, spb, wb, wob, kb, vtb);
    qkv_mfma<<<dim3(64, 24), 256, 0, stream>>>(wb, xb, spb, qb, kb, vtb);
    attn_mfma<<<dim3(1024), 256, 0, stream>>>(qb, kb, vtb, obb);
    out_mfma<<<dim3(64, 4), 256, 0, stream>>>(wob, obb, out);
}